// Round 3
// baseline (214.251 us; speedup 1.0000x reference)
//
#include <hip/hip_runtime.h>

#define BB 16
#define CC 768
#define DD 128
#define NN 4096

typedef float f32x4 __attribute__((ext_vector_type(4)));
typedef __bf16 bf16x8 __attribute__((ext_vector_type(8)));
typedef __bf16 bf16x4 __attribute__((ext_vector_type(4)));

__device__ __forceinline__ float wave_reduce_max(float x) {
#pragma unroll
  for (int off = 32; off > 0; off >>= 1) x = fmaxf(x, __shfl_xor(x, off, 64));
  return x;
}
__device__ __forceinline__ float wave_reduce_sum(float x) {
#pragma unroll
  for (int off = 32; off > 0; off >>= 1) x += __shfl_xor(x, off, 64);
  return x;
}

// K1: per (b,d) row: softmax stats over n (max, 1/sum). Also zero hmat accumulator.
// softmax(dt + A[d]) over n == softmax(dt) over n (A constant along axis) -> A unused.
__global__ __launch_bounds__(256) void k_stats(const float* __restrict__ BCdt,
                                               float* __restrict__ stats,
                                               float* __restrict__ hmat) {
  int blk = blockIdx.x;  // b*128 + d
  int b = blk >> 7, d = blk & 127;
  const float4* row = (const float4*)(BCdt + ((size_t)b * (2 * DD) + (DD + d)) * NN);
  int t = threadIdx.x;
  float4 v[4];
  float mx = -3.0e38f;
#pragma unroll
  for (int i = 0; i < 4; ++i) {
    v[i] = row[t + 256 * i];
    mx = fmaxf(mx, fmaxf(fmaxf(v[i].x, v[i].y), fmaxf(v[i].z, v[i].w)));
  }
  __shared__ float red[8];
  float wm = wave_reduce_max(mx);
  int wid = t >> 6;
  if ((t & 63) == 0) red[wid] = wm;
  __syncthreads();
  mx = fmaxf(fmaxf(red[0], red[1]), fmaxf(red[2], red[3]));
  float s = 0.f;
#pragma unroll
  for (int i = 0; i < 4; ++i)
    s += __expf(v[i].x - mx) + __expf(v[i].y - mx) + __expf(v[i].z - mx) + __expf(v[i].w - mx);
  float ws = wave_reduce_sum(s);
  if ((t & 63) == 0) red[4 + wid] = ws;
  __syncthreads();
  if (t == 0) {
    float tot = red[4] + red[5] + red[6] + red[7];
    stats[2 * blk] = mx;
    stats[2 * blk + 1] = 1.0f / tot;
  }
  float* hz = hmat + (size_t)blk * 768;
#pragma unroll
  for (int i = 0; i < 3; ++i) hz[t + 256 * i] = 0.f;
}

// K1b: AB = softmax(dt)*BC -> bf16 [b][d][n]; BCt = BC^T -> bf16 [b][n][d].
__global__ __launch_bounds__(256) void k_prep(const float* __restrict__ BCdt,
                                              const float* __restrict__ stats,
                                              __bf16* __restrict__ AB,
                                              __bf16* __restrict__ BCt) {
  int blk = blockIdx.x;  // b*128 + dtile*64 + ntile
  int ntile = blk & 63;
  int dtile = (blk >> 6) & 1;
  int b = blk >> 7;
  int d0 = dtile * 64, n0 = ntile * 64;
  __shared__ __bf16 Ls[64][76];
  int t = threadIdx.x;
  int r = t >> 4;
  int cg = t & 15;
  const float* base = BCdt + (size_t)b * (2 * DD) * NN;
#pragma unroll
  for (int p = 0; p < 4; ++p) {
    int dl = r + p * 16;
    int d = d0 + dl;
    float4 bc = *(const float4*)(base + (size_t)d * NN + n0 + cg * 4);
    float4 dt = *(const float4*)(base + (size_t)(DD + d) * NN + n0 + cg * 4);
    float mx = stats[2 * (b * DD + d)];
    float inv = stats[2 * (b * DD + d) + 1];
    bf16x4 abv;
    abv[0] = (__bf16)(__expf(dt.x - mx) * inv * bc.x);
    abv[1] = (__bf16)(__expf(dt.y - mx) * inv * bc.y);
    abv[2] = (__bf16)(__expf(dt.z - mx) * inv * bc.z);
    abv[3] = (__bf16)(__expf(dt.w - mx) * inv * bc.w);
    *(bf16x4*)(AB + ((size_t)(b * DD + d)) * NN + n0 + cg * 4) = abv;
    bf16x4 bcv;
    bcv[0] = (__bf16)bc.x; bcv[1] = (__bf16)bc.y; bcv[2] = (__bf16)bc.z; bcv[3] = (__bf16)bc.w;
    *(bf16x4*)(&Ls[dl][cg * 4]) = bcv;
  }
  __syncthreads();
#pragma unroll
  for (int p = 0; p < 4; ++p) {
    int j = r + p * 16;
    bf16x4 v;
#pragma unroll
    for (int k = 0; k < 4; ++k) v[k] = Ls[cg * 4 + k][j];
    *(bf16x4*)(BCt + ((size_t)b * NN + n0 + j) * DD + d0 + cg * 4) = v;
  }
}

// K2: hmat[b][c][d] += sum_n x[b][c][n]*AB[b][d][n]; 128x128 tile, split-K x16.
// X staged via LDS (needs fp32->bf16 cvt); B-fragments read DIRECT from global AB
// (L2/L3-resident; one 64-lane frag load touches 16 fully-utilized cache lines).
__global__ __launch_bounds__(256) void k_hmat(const float* __restrict__ x,
                                              const __bf16* __restrict__ AB,
                                              float* __restrict__ hmat) {
  int blk = blockIdx.x;  // ((b*6 + mt)<<4) | q
  int q = blk & 15;
  int rest = blk >> 4;
  int mt = rest % 6;
  int b = rest / 6;
  int c0 = mt * 128;
  int kbase = q * 256;
  __shared__ __bf16 Xs[128][72];  // 18432 B
  int t = threadIdx.x;
  int lane = t & 63, w = t >> 6;
  int wr = w >> 1, wc = w & 1;
  int fr = lane & 15, fg = lane >> 4;
  f32x4 acc[4][4] = {};
  const float* xb = x + ((size_t)b * CC + c0) * NN + kbase;
  const __bf16* abb = AB + ((size_t)b * DD + wc * 64 + fr) * NN + kbase;
  int rr = t >> 4, cg = t & 15;
  for (int s = 0; s < 4; ++s) {
    int koff = s * 64;
#pragma unroll
    for (int p = 0; p < 8; ++p) {  // stage X: 128 rows x 64 fp32 -> bf16
      int row = rr + p * 16;
      float4 f = *(const float4*)(xb + (size_t)row * NN + koff + cg * 4);
      bf16x4 v;
      v[0] = (__bf16)f.x; v[1] = (__bf16)f.y; v[2] = (__bf16)f.z; v[3] = (__bf16)f.w;
      *(bf16x4*)(&Xs[row][cg * 4]) = v;
    }
    __syncthreads();
#pragma unroll
    for (int kk = 0; kk < 2; ++kk) {
      bf16x8 a[4], bfr[4];
#pragma unroll
      for (int i = 0; i < 4; ++i)
        a[i] = *(const bf16x8*)(&Xs[wr * 64 + i * 16 + fr][kk * 32 + fg * 8]);
#pragma unroll
      for (int i = 0; i < 4; ++i)
        bfr[i] = *(const bf16x8*)(abb + (size_t)(i * 16) * NN + koff + kk * 32 + fg * 8);
#pragma unroll
      for (int mi = 0; mi < 4; ++mi)
#pragma unroll
        for (int ni = 0; ni < 4; ++ni)
          acc[mi][ni] = __builtin_amdgcn_mfma_f32_16x16x32_bf16(a[mi], bfr[ni], acc[mi][ni], 0, 0, 0);
    }
    __syncthreads();
  }
  float* hb = hmat + (size_t)b * CC * DD;
#pragma unroll
  for (int mi = 0; mi < 4; ++mi)
#pragma unroll
    for (int ni = 0; ni < 4; ++ni)
#pragma unroll
      for (int ri = 0; ri < 4; ++ri) {
        int rowc = c0 + wr * 64 + mi * 16 + fg * 4 + ri;
        int cold = wc * 64 + ni * 16 + fr;
        atomicAdd(hb + (size_t)rowc * DD + cold, acc[mi][ni][ri]);
      }
}

// K2b: hmat fp32 -> bf16 (so k_y A-fragments are single 16B loads).
__global__ __launch_bounds__(256) void k_conv(const float* __restrict__ hmat,
                                              __bf16* __restrict__ hmatB) {
  size_t base = (size_t)blockIdx.x * 2048 + (size_t)threadIdx.x * 8;
  float4 f0 = *(const float4*)(hmat + base);
  float4 f1 = *(const float4*)(hmat + base + 4);
  bf16x8 v;
  v[0] = (__bf16)f0.x; v[1] = (__bf16)f0.y; v[2] = (__bf16)f0.z; v[3] = (__bf16)f0.w;
  v[4] = (__bf16)f1.x; v[5] = (__bf16)f1.y; v[6] = (__bf16)f1.z; v[7] = (__bf16)f1.w;
  *(bf16x8*)(hmatB + base) = v;
}

// K3: y[b][c][n] = sum_d hmatB[b][c][d]*BCt[b][n][d]; 128c x 128n tile, K=128.
// Inputs cache-resident -> fragments loaded DIRECT from global (no input LDS).
// Output restaged through a 64x132 f32 LDS tile in two half phases for coalesced
// float4 stores. LDS 33.8KB -> 4 blocks/CU.
__global__ __launch_bounds__(256, 4) void k_y(const __bf16* __restrict__ hmatB,
                                              const __bf16* __restrict__ BCt,
                                              float* __restrict__ y) {
  int blk = blockIdx.x;  // ((b*6+mt)<<5) | nt
  int nt = blk & 31;
  int rest = blk >> 5;
  int mt = rest % 6;
  int b = rest / 6;
  int c0 = mt * 128, n0 = nt * 128;
  __shared__ float St[64][132];
  int t = threadIdx.x;
  int lane = t & 63, w = t >> 6;
  int wr = w >> 1, wc = w & 1;
  int fr = lane & 15, fg = lane >> 4;
  const __bf16* hb = hmatB + ((size_t)b * CC + c0 + wr * 64 + fr) * DD;
  const __bf16* bb = BCt + ((size_t)b * NN + n0 + wc * 64 + fr) * DD;
  f32x4 acc[4][4] = {};
#pragma unroll
  for (int kk = 0; kk < 4; ++kk) {
    bf16x8 a[4], bfr[4];
#pragma unroll
    for (int i = 0; i < 4; ++i)
      a[i] = *(const bf16x8*)(hb + (size_t)(i * 16) * DD + kk * 32 + fg * 8);
#pragma unroll
    for (int i = 0; i < 4; ++i)
      bfr[i] = *(const bf16x8*)(bb + (size_t)(i * 16) * DD + kk * 32 + fg * 8);
#pragma unroll
    for (int mi = 0; mi < 4; ++mi)
#pragma unroll
      for (int ni = 0; ni < 4; ++ni)
        acc[mi][ni] = __builtin_amdgcn_mfma_f32_16x16x32_bf16(a[mi], bfr[ni], acc[mi][ni], 0, 0, 0);
  }
  float* yb = y + ((size_t)b * CC + c0) * NN + n0;
  int rr3 = t >> 5, cg3 = t & 31;
#pragma unroll
  for (int half = 0; half < 2; ++half) {
    if (wr == half) {
#pragma unroll
      for (int mi = 0; mi < 4; ++mi)
#pragma unroll
        for (int ni = 0; ni < 4; ++ni)
#pragma unroll
          for (int ri = 0; ri < 4; ++ri)
            St[mi * 16 + fg * 4 + ri][wc * 64 + ni * 16 + fr] = acc[mi][ni][ri];
    }
    __syncthreads();
#pragma unroll
    for (int p = 0; p < 8; ++p) {
      int lrow = rr3 + p * 8;
      float4 v = *(const float4*)(&St[lrow][cg3 * 4]);
      *(float4*)(yb + (size_t)(half * 64 + lrow) * NN + cg3 * 4) = v;
    }
    __syncthreads();
  }
}

extern "C" void kernel_launch(void* const* d_in, const int* in_sizes, int n_in,
                              void* d_out, int out_size, void* d_ws, size_t ws_size,
                              hipStream_t stream) {
  (void)in_sizes; (void)n_in; (void)out_size; (void)ws_size;
  const float* BCdt = (const float*)d_in[0];
  const float* x = (const float*)d_in[1];
  // d_in[2] (A) unused: softmax shift-invariance.
  char* ws = (char*)d_ws;
  size_t offAB = 0;
  size_t offBCt = offAB + (size_t)BB * DD * NN * 2;    // 16.78 MB
  size_t offH = offBCt + (size_t)BB * NN * DD * 2;     // +16.78 MB
  size_t offHB = offH + (size_t)BB * CC * DD * 4;      // +6.29 MB
  size_t offS = offHB + (size_t)BB * CC * DD * 2;      // +3.15 MB
  __bf16* AB = (__bf16*)(ws + offAB);
  __bf16* BCt = (__bf16*)(ws + offBCt);
  float* hmat = (float*)(ws + offH);
  __bf16* hmatB = (__bf16*)(ws + offHB);
  float* stats = (float*)(ws + offS);
  float* y = (float*)d_out;

  k_stats<<<dim3(BB * DD), dim3(256), 0, stream>>>(BCdt, stats, hmat);
  k_prep<<<dim3(BB * 2 * 64), dim3(256), 0, stream>>>(BCdt, stats, AB, BCt);
  k_hmat<<<dim3(BB * 6 * 16), dim3(256), 0, stream>>>(x, AB, hmat);
  k_conv<<<dim3(768), dim3(256), 0, stream>>>(hmat, hmatB);
  k_y<<<dim3(BB * 6 * 32), dim3(256), 0, stream>>>(hmatB, BCt, y);
}

// Round 4
// 165.558 us; speedup vs baseline: 1.2941x; 1.2941x over previous
//
#include <hip/hip_runtime.h>

#define BB 16
#define CC 768
#define DD 128
#define NN 4096

typedef float f32x4 __attribute__((ext_vector_type(4)));
typedef __bf16 bf16x8 __attribute__((ext_vector_type(8)));
typedef __bf16 bf16x4 __attribute__((ext_vector_type(4)));

__device__ __forceinline__ float wave_reduce_max(float x) {
#pragma unroll
  for (int off = 32; off > 0; off >>= 1) x = fmaxf(x, __shfl_xor(x, off, 64));
  return x;
}
__device__ __forceinline__ float wave_reduce_sum(float x) {
#pragma unroll
  for (int off = 32; off > 0; off >>= 1) x += __shfl_xor(x, off, 64);
  return x;
}

// K1: per (b,d) row: softmax stats over n (max, 1/sum).
// softmax(dt + A[d]) over n == softmax(dt) over n (A constant along axis) -> A unused.
__global__ __launch_bounds__(256) void k_stats(const float* __restrict__ BCdt,
                                               float* __restrict__ stats) {
  int blk = blockIdx.x;  // b*128 + d
  int b = blk >> 7, d = blk & 127;
  const float4* row = (const float4*)(BCdt + ((size_t)b * (2 * DD) + (DD + d)) * NN);
  int t = threadIdx.x;
  float4 v[4];
  float mx = -3.0e38f;
#pragma unroll
  for (int i = 0; i < 4; ++i) {
    v[i] = row[t + 256 * i];
    mx = fmaxf(mx, fmaxf(fmaxf(v[i].x, v[i].y), fmaxf(v[i].z, v[i].w)));
  }
  __shared__ float red[8];
  float wm = wave_reduce_max(mx);
  int wid = t >> 6;
  if ((t & 63) == 0) red[wid] = wm;
  __syncthreads();
  mx = fmaxf(fmaxf(red[0], red[1]), fmaxf(red[2], red[3]));
  float s = 0.f;
#pragma unroll
  for (int i = 0; i < 4; ++i)
    s += __expf(v[i].x - mx) + __expf(v[i].y - mx) + __expf(v[i].z - mx) + __expf(v[i].w - mx);
  float ws = wave_reduce_sum(s);
  if ((t & 63) == 0) red[4 + wid] = ws;
  __syncthreads();
  if (t == 0) {
    float tot = red[4] + red[5] + red[6] + red[7];
    stats[2 * blk] = mx;
    stats[2 * blk + 1] = 1.0f / tot;
  }
}

// K1b: AB = softmax(dt)*BC -> bf16 [b][d][n]; BCt = BC^T -> bf16 [b][n][d].
__global__ __launch_bounds__(256) void k_prep(const float* __restrict__ BCdt,
                                              const float* __restrict__ stats,
                                              __bf16* __restrict__ AB,
                                              __bf16* __restrict__ BCt) {
  int blk = blockIdx.x;  // b*128 + dtile*64 + ntile
  int ntile = blk & 63;
  int dtile = (blk >> 6) & 1;
  int b = blk >> 7;
  int d0 = dtile * 64, n0 = ntile * 64;
  __shared__ __bf16 Ls[64][76];
  int t = threadIdx.x;
  int r = t >> 4;
  int cg = t & 15;
  const float* base = BCdt + (size_t)b * (2 * DD) * NN;
#pragma unroll
  for (int p = 0; p < 4; ++p) {
    int dl = r + p * 16;
    int d = d0 + dl;
    float4 bc = *(const float4*)(base + (size_t)d * NN + n0 + cg * 4);
    float4 dt = *(const float4*)(base + (size_t)(DD + d) * NN + n0 + cg * 4);
    float mx = stats[2 * (b * DD + d)];
    float inv = stats[2 * (b * DD + d) + 1];
    bf16x4 abv;
    abv[0] = (__bf16)(__expf(dt.x - mx) * inv * bc.x);
    abv[1] = (__bf16)(__expf(dt.y - mx) * inv * bc.y);
    abv[2] = (__bf16)(__expf(dt.z - mx) * inv * bc.z);
    abv[3] = (__bf16)(__expf(dt.w - mx) * inv * bc.w);
    *(bf16x4*)(AB + ((size_t)(b * DD + d)) * NN + n0 + cg * 4) = abv;
    bf16x4 bcv;
    bcv[0] = (__bf16)bc.x; bcv[1] = (__bf16)bc.y; bcv[2] = (__bf16)bc.z; bcv[3] = (__bf16)bc.w;
    *(bf16x4*)(&Ls[dl][cg * 4]) = bcv;
  }
  __syncthreads();
#pragma unroll
  for (int p = 0; p < 4; ++p) {
    int j = r + p * 16;
    bf16x4 v;
#pragma unroll
    for (int k = 0; k < 4; ++k) v[k] = Ls[cg * 4 + k][j];
    *(bf16x4*)(BCt + ((size_t)b * NN + n0 + j) * DD + d0 + cg * 4) = v;
  }
}

// K2: partial hmat: hpart[q][b][c][d] = sum_{n in slab q} x[b][c][n]*AB[b][d][n].
// 128x128 tile, split-K x8, X+AB LDS-staged, NO ATOMICS: bf16 partials restaged
// through LDS and streamed out 16B-coalesced. hpart lives in d_out (k_y
// overwrites d_out afterwards; stream-ordered so no hazard).
__global__ __launch_bounds__(256) void k_hmat(const float* __restrict__ x,
                                              const __bf16* __restrict__ AB,
                                              __bf16* __restrict__ hpart) {
  int blk = blockIdx.x;  // ((b*6 + mt)<<3) | q
  int q = blk & 7;
  int rest = blk >> 3;
  int mt = rest % 6;
  int b = rest / 6;
  int c0 = mt * 128;
  int kbase = q * 512;
  __shared__ __align__(16) char smem[36864];
  __bf16(*Xs)[72] = (__bf16(*)[72])smem;            // [c][k] 18432B
  __bf16(*ABs)[72] = (__bf16(*)[72])(smem + 18432); // [d][k] 18432B
  __bf16(*Ls16)[136] = (__bf16(*)[136])smem;        // epilogue restage 17408B
  int t = threadIdx.x;
  int lane = t & 63, w = t >> 6;
  int wr = w >> 1, wc = w & 1;
  int fr = lane & 15, fg = lane >> 4;
  f32x4 acc[4][4] = {};
  const float* xb = x + ((size_t)b * CC + c0) * NN + kbase;
  const __bf16* abb = AB + (size_t)b * DD * NN + kbase;
  int rr = t >> 4, cg = t & 15;
  int rr2 = t >> 3, cg2 = t & 7;
  for (int s = 0; s < 8; ++s) {
    int koff = s * 64;
#pragma unroll
    for (int p = 0; p < 8; ++p) {  // stage X: 128 rows x 64 fp32 -> bf16
      int row = rr + p * 16;
      float4 f = *(const float4*)(xb + (size_t)row * NN + koff + cg * 4);
      bf16x4 v;
      v[0] = (__bf16)f.x; v[1] = (__bf16)f.y; v[2] = (__bf16)f.z; v[3] = (__bf16)f.w;
      *(bf16x4*)(&Xs[row][cg * 4]) = v;
    }
#pragma unroll
    for (int p = 0; p < 4; ++p) {  // stage AB: 128 rows x 64 bf16, 16B copies
      int row = rr2 + p * 32;
      uint4 u = *(const uint4*)(abb + (size_t)row * NN + koff + cg2 * 8);
      *(uint4*)(&ABs[row][cg2 * 8]) = u;
    }
    __syncthreads();
#pragma unroll
    for (int kk = 0; kk < 2; ++kk) {
      bf16x8 a[4], bfr[4];
#pragma unroll
      for (int i = 0; i < 4; ++i)
        a[i] = *(const bf16x8*)(&Xs[wr * 64 + i * 16 + fr][kk * 32 + fg * 8]);
#pragma unroll
      for (int i = 0; i < 4; ++i)
        bfr[i] = *(const bf16x8*)(&ABs[wc * 64 + i * 16 + fr][kk * 32 + fg * 8]);
#pragma unroll
      for (int mi = 0; mi < 4; ++mi)
#pragma unroll
        for (int ni = 0; ni < 4; ++ni)
          acc[mi][ni] = __builtin_amdgcn_mfma_f32_16x16x32_bf16(a[mi], bfr[ni], acc[mi][ni], 0, 0, 0);
    }
    __syncthreads();
  }
  // Epilogue: bf16 partial tile, LDS restage in two 64-row halves, 16B stores.
  __bf16* hp = hpart + (((size_t)q * BB + b) * CC + c0) * DD;
#pragma unroll
  for (int half = 0; half < 2; ++half) {
    if (wr == half) {
#pragma unroll
      for (int mi = 0; mi < 4; ++mi)
#pragma unroll
        for (int ni = 0; ni < 4; ++ni)
#pragma unroll
          for (int ri = 0; ri < 4; ++ri)
            Ls16[mi * 16 + fg * 4 + ri][wc * 64 + ni * 16 + fr] = (__bf16)acc[mi][ni][ri];
    }
    __syncthreads();
#pragma unroll
    for (int j = 0; j < 4; ++j) {
      int chunk = j * 256 + t;  // 1024 chunks = 64 rows x 16 x (8 bf16)
      int row = chunk >> 4, col8 = chunk & 15;
      bf16x8 v = *(const bf16x8*)(&Ls16[row][col8 * 8]);
      *(bf16x8*)(hp + (size_t)(half * 64 + row) * DD + col8 * 8) = v;
    }
    __syncthreads();
  }
}

// K2b: hmatB = sum_q hpart[q] (fp32 accum) -> bf16.
__global__ __launch_bounds__(256) void k_conv(const __bf16* __restrict__ hpart,
                                              __bf16* __restrict__ hmatB) {
  size_t idx = (size_t)blockIdx.x * 2048 + (size_t)threadIdx.x * 8;
  const size_t stride = (size_t)BB * CC * DD;
  float s[8] = {};
#pragma unroll
  for (int q = 0; q < 8; ++q) {
    bf16x8 v = *(const bf16x8*)(hpart + q * stride + idx);
#pragma unroll
    for (int j = 0; j < 8; ++j) s[j] += (float)v[j];
  }
  bf16x8 o;
#pragma unroll
  for (int j = 0; j < 8; ++j) o[j] = (__bf16)s[j];
  *(bf16x8*)(hmatB + idx) = o;
}

// K3: y[b][c][n] = sum_d hmatB[b][c][d]*BCt[b][n][d]; 128c x 128n tile, K=128.
// Inputs cache-resident -> fragments direct from global; output restaged via LDS.
__global__ __launch_bounds__(256, 4) void k_y(const __bf16* __restrict__ hmatB,
                                              const __bf16* __restrict__ BCt,
                                              float* __restrict__ y) {
  int blk = blockIdx.x;  // ((b*6+mt)<<5) | nt
  int nt = blk & 31;
  int rest = blk >> 5;
  int mt = rest % 6;
  int b = rest / 6;
  int c0 = mt * 128, n0 = nt * 128;
  __shared__ float St[64][132];
  int t = threadIdx.x;
  int lane = t & 63, w = t >> 6;
  int wr = w >> 1, wc = w & 1;
  int fr = lane & 15, fg = lane >> 4;
  const __bf16* hb = hmatB + ((size_t)b * CC + c0 + wr * 64 + fr) * DD;
  const __bf16* bb = BCt + ((size_t)b * NN + n0 + wc * 64 + fr) * DD;
  f32x4 acc[4][4] = {};
#pragma unroll
  for (int kk = 0; kk < 4; ++kk) {
    bf16x8 a[4], bfr[4];
#pragma unroll
    for (int i = 0; i < 4; ++i)
      a[i] = *(const bf16x8*)(hb + (size_t)(i * 16) * DD + kk * 32 + fg * 8);
#pragma unroll
    for (int i = 0; i < 4; ++i)
      bfr[i] = *(const bf16x8*)(bb + (size_t)(i * 16) * DD + kk * 32 + fg * 8);
#pragma unroll
    for (int mi = 0; mi < 4; ++mi)
#pragma unroll
      for (int ni = 0; ni < 4; ++ni)
        acc[mi][ni] = __builtin_amdgcn_mfma_f32_16x16x32_bf16(a[mi], bfr[ni], acc[mi][ni], 0, 0, 0);
  }
  float* yb = y + ((size_t)b * CC + c0) * NN + n0;
  int rr3 = t >> 5, cg3 = t & 31;
#pragma unroll
  for (int half = 0; half < 2; ++half) {
    if (wr == half) {
#pragma unroll
      for (int mi = 0; mi < 4; ++mi)
#pragma unroll
        for (int ni = 0; ni < 4; ++ni)
#pragma unroll
          for (int ri = 0; ri < 4; ++ri)
            St[mi * 16 + fg * 4 + ri][wc * 64 + ni * 16 + fr] = acc[mi][ni][ri];
    }
    __syncthreads();
#pragma unroll
    for (int p = 0; p < 8; ++p) {
      int lrow = rr3 + p * 8;
      float4 v = *(const float4*)(&St[lrow][cg3 * 4]);
      *(float4*)(yb + (size_t)(half * 64 + lrow) * NN + cg3 * 4) = v;
    }
    __syncthreads();
  }
}

extern "C" void kernel_launch(void* const* d_in, const int* in_sizes, int n_in,
                              void* d_out, int out_size, void* d_ws, size_t ws_size,
                              hipStream_t stream) {
  (void)in_sizes; (void)n_in; (void)out_size; (void)ws_size;
  const float* BCdt = (const float*)d_in[0];
  const float* x = (const float*)d_in[1];
  // d_in[2] (A) unused: softmax shift-invariance.
  char* ws = (char*)d_ws;
  size_t offAB = 0;
  size_t offBCt = offAB + (size_t)BB * DD * NN * 2;   // 16.78 MB
  size_t offHB = offBCt + (size_t)BB * NN * DD * 2;   // +16.78 MB
  size_t offS = offHB + (size_t)BB * CC * DD * 2;     // +3.15 MB
  __bf16* AB = (__bf16*)(ws + offAB);
  __bf16* BCt = (__bf16*)(ws + offBCt);
  __bf16* hmatB = (__bf16*)(ws + offHB);
  float* stats = (float*)(ws + offS);
  // Partial sums live in d_out (25.2 MB of 201 MB); k_y overwrites d_out last.
  __bf16* hpart = (__bf16*)d_out;
  float* y = (float*)d_out;

  k_stats<<<dim3(BB * DD), dim3(256), 0, stream>>>(BCdt, stats);
  k_prep<<<dim3(BB * 2 * 64), dim3(256), 0, stream>>>(BCdt, stats, AB, BCt);
  k_hmat<<<dim3(BB * 6 * 8), dim3(256), 0, stream>>>(x, AB, hpart);
  k_conv<<<dim3(768), dim3(256), 0, stream>>>(hpart, hmatB);
  k_y<<<dim3(BB * 6 * 32), dim3(256), 0, stream>>>(hmatB, BCt, y);
}